// Round 10
// baseline (442.885 us; speedup 1.0000x reference)
//
#include <hip/hip_runtime.h>
#include <stdint.h>

typedef __attribute__((ext_vector_type(8))) _Float16 half8;
typedef __attribute__((ext_vector_type(4))) float f32x4;

#define CDIM 256
#define KCODES 1024
#define NPTS 131072
#define ZQ_ELEMS 33554432u
#define CAP 32768
#define MARGIN 3.0e-4f

// ws layout (bytes)
#define WS_IMG 0                          // 512 KiB fp16-hi fragment-major codebook image; ALIASED by cbT after vq_dist
#define WS_S2 (16 * 65536)                // 1024 floats (np-pairwise ||e||^2)
#define WS_IDX (WS_S2 + 4096)             // 131072 ints
#define WS_PART (WS_IDX + NPTS * 4)       // 16384 floats
#define WS_CNT (WS_PART + 65536)          // 1 int (+pad)
#define WS_LIST (WS_CNT + 64)             // CAP ints

// EXACT replica of numpy pairwise_sum over fl(x[c]*x[c]) for n=256 (verified round 3).
__device__ __forceinline__ float np_pairwise_sq_256(const float* x) {
    float res[2];
#pragma unroll
    for (int h = 0; h < 2; h++) {
        const float* a = x + h * 128;
        float r[8];
#pragma unroll
        for (int j = 0; j < 8; j++) r[j] = __fmul_rn(a[j], a[j]);
#pragma unroll
        for (int i = 8; i < 128; i += 8)
#pragma unroll
            for (int j = 0; j < 8; j++)
                r[j] = __fadd_rn(r[j], __fmul_rn(a[i + j], a[i + j]));
        res[h] = __fadd_rn(__fadd_rn(__fadd_rn(r[0], r[1]), __fadd_rn(r[2], r[3])),
                           __fadd_rn(__fadd_rn(r[4], r[5]), __fadd_rn(r[6], r[7])));
    }
    return __fadd_rn(res[0], res[1]);
}

// ---------------- prep: fp16-hi FRAGMENT-MAJOR codebook image + counter reset ----------
// Chunk = 64 codes = 32 KB = 32 slots of 1 KB. Slot s = (ks*2+cth)*2 + q holds the exact
// 1KB one wave reads with one coalesced global_load_dwordx4 at cbase + s*1024 + lane*16:
// lane (l4,l15) = code (cth*2+q)*16+l15, channels ks*32+l4*8 .. +8.
__global__ __launch_bounds__(256) void vq_prep(const float* __restrict__ cb,
                                               unsigned char* __restrict__ img,
                                               int* __restrict__ cnt) {
    int t = threadIdx.x;
    if (blockIdx.x == 0 && t == 0) *cnt = 0;
    int codeLocal = t >> 5;      // 0..7
    int cg = t & 31;             // 8-channel group
    int k = blockIdx.x * 8 + codeLocal;
    const float* row = cb + k * CDIM + cg * 8;
    union H { _Float16 h[8]; uint4 u; } hi;
#pragma unroll
    for (int j = 0; j < 8; j++) hi.h[j] = (_Float16)(row[j] * 1024.f);
    int chunk = k >> 6, rowi = k & 63;
    int ks = cg >> 2, l4 = cg & 3;
    int cth = rowi >> 5, q = (rowi >> 4) & 1, l15 = rowi & 15;
    int lane = l4 * 16 + l15;
    *(uint4*)(img + chunk * 32768 + (((ks * 2 + cth) * 2 + q) << 10) + lane * 16) = hi.u;
}

// ---------------- s2[k] = np-pairwise sum of codebook row squares ----------------
__global__ __launch_bounds__(256) void vq_s2prep(const float* __restrict__ cb,
                                                 float* __restrict__ s2) {
    int k = blockIdx.x * 256 + threadIdx.x;
    float e[256];
#pragma unroll
    for (int c = 0; c < 256; c++) e[c] = cb[(size_t)k * CDIM + c];
    s2[k] = np_pairwise_sq_256(e);
}

// ---------------- pass 1: 2-term fp16 MFMA distances + argmin + near-tie flagging --------
// B-fragments read DIRECTLY from the L2-resident 512KB image (no LDS staging, no
// barriers in the K-loop). A-tile loaded coalesced via a 16KB LDS slice buffer.
__global__ __launch_bounds__(256, 2) void vq_dist(const float* __restrict__ z,
                                                  const unsigned char* __restrict__ img,
                                                  const float* __restrict__ s2g,
                                                  int* __restrict__ outIdx,
                                                  int* __restrict__ cnt,
                                                  int* __restrict__ list) {
    __shared__ __align__(16) unsigned char az[16384];
    __shared__ float e2s[1024];
    int t = threadIdx.x;
    int lane = t & 63, wave = t >> 6;
    int l15 = lane & 15, l4 = lane >> 4;
    int blk0 = blockIdx.x * 128;               // block's first point (hw window aligned 128)
    int wbase = blk0 + wave * 32;
    int b = blk0 >> 12;
    int hwb0 = blk0 & 4095;
    const float* zb = z + (size_t)b * (CDIM * 4096);

#pragma unroll
    for (int i = 0; i < 4; i++) e2s[t + i * 256] = s2g[t + i * 256];

    // coalesced A-tile prologue: 8 slices of [32ch x 128hw] = 16KB each via LDS
    half8 aHi[2][8], aLo[2][8];
#pragma unroll
    for (int ks = 0; ks < 8; ks++) {
        __syncthreads();   // az free (previous slice's readers done)
#pragma unroll
        for (int i = 0; i < 4; i++) {
            int u = i * 256 + t;               // 16B unit
            int row = u >> 5, col4 = u & 31;   // row=local channel, 128 floats/row
            const float* gsrc = zb + (size_t)(ks * 32 + row) * 4096 + hwb0 + col4 * 4;
            __builtin_amdgcn_global_load_lds(
                (const __attribute__((address_space(1))) void*)gsrc,
                (__attribute__((address_space(3))) void*)(az + (size_t)u * 16), 16, 0, 0);
        }
        __syncthreads();   // slice ready
#pragma unroll
        for (int m = 0; m < 2; m++) {
            half8 h, l;
#pragma unroll
            for (int j = 0; j < 8; j++) {
                float f = *(const float*)(az +
                        (size_t)(((l4 * 8 + j) * 128) + wave * 32 + m * 16 + l15) * 4) * 32.f;
                _Float16 fh = (_Float16)f;
                h[j] = fh;
                l[j] = (_Float16)(f - (float)fh);
            }
            aHi[m][ks] = h;
            aLo[m][ks] = l;
        }
    }

    float bestv[2][4], bestv2[2][4];
    int besti[2][4];
#pragma unroll
    for (int m = 0; m < 2; m++)
#pragma unroll
        for (int j = 0; j < 4; j++) { bestv[m][j] = 3.0e38f; bestv2[m][j] = 3.0e38f; besti[m][j] = 0; }

    // barrier-free K-loop: B-fragments straight from L2
    const unsigned char* cbase0 = img + (size_t)lane * 16;
    for (int chunk = 0; chunk < 16; chunk++) {
        const unsigned char* cbase = cbase0 + (size_t)chunk * 32768;

        f32x4 accH[2][4], accL[2][4];
#pragma unroll
        for (int m = 0; m < 2; m++)
#pragma unroll
            for (int ct = 0; ct < 4; ct++) {
                accH[m][ct] = (f32x4){0.f, 0.f, 0.f, 0.f};
                accL[m][ct] = (f32x4){0.f, 0.f, 0.f, 0.f};
            }

#pragma unroll
        for (int ks = 0; ks < 8; ks++) {
#pragma unroll
            for (int cth = 0; cth < 2; cth++) {
                const unsigned char* fb = cbase + (((ks * 2 + cth) * 2) << 10);
                half8 bh0 = *(const half8*)(fb);
                half8 bh1 = *(const half8*)(fb + 1024);
#pragma unroll
                for (int m = 0; m < 2; m++) {
                    int ct0 = cth * 2;
                    accH[m][ct0] = __builtin_amdgcn_mfma_f32_16x16x32_f16(aHi[m][ks], bh0, accH[m][ct0], 0, 0, 0);
                    accL[m][ct0] = __builtin_amdgcn_mfma_f32_16x16x32_f16(aLo[m][ks], bh0, accL[m][ct0], 0, 0, 0);
                    accH[m][ct0 + 1] = __builtin_amdgcn_mfma_f32_16x16x32_f16(aHi[m][ks], bh1, accH[m][ct0 + 1], 0, 0, 0);
                    accL[m][ct0 + 1] = __builtin_amdgcn_mfma_f32_16x16x32_f16(aLo[m][ks], bh1, accL[m][ct0 + 1], 0, 0, 0);
                }
            }
        }
        // d' = s2 - (accH+accL)/16384; track best + 2nd best
#pragma unroll
        for (int ct = 0; ct < 4; ct++) {
            int code = chunk * 64 + ct * 16 + l15;
            float ev = e2s[code];
#pragma unroll
            for (int m = 0; m < 2; m++)
#pragma unroll
                for (int j = 0; j < 4; j++) {
                    float a = accH[m][ct][j] + accL[m][ct][j];
                    float s = fmaf(a, -6.103515625e-05f, ev);
                    if (s < bestv[m][j]) { bestv2[m][j] = bestv[m][j]; bestv[m][j] = s; besti[m][j] = code; }
                    else if (s < bestv2[m][j]) bestv2[m][j] = s;
                }
        }
    }

#pragma unroll
    for (int m = 0; m < 2; m++)
#pragma unroll
        for (int j = 0; j < 4; j++) {
            float v = bestv[m][j], v2 = bestv2[m][j];
            int idx = besti[m][j];
#pragma unroll
            for (int off = 1; off < 16; off <<= 1) {
                float ov = __shfl_xor(v, off);
                float ov2 = __shfl_xor(v2, off);
                int oi = __shfl_xor(idx, off);
                if (ov < v || (ov == v && oi < idx)) { v2 = fminf(v, ov2); v = ov; idx = oi; }
                else v2 = fminf(v2, ov);
            }
            if (l15 == 0) {
                int p = wbase + m * 16 + l4 * 4 + j;
                outIdx[p] = idx;
                if (v2 - v < MARGIN) {
                    int pos = atomicAdd(cnt, 1);
                    if (pos < CAP) list[pos] = p;
                }
            }
        }
}

// ---------------- transpose codebook into cbT[256][1024] (aliases dead img region) --------
__global__ __launch_bounds__(256) void vq_cbt(const float* __restrict__ cb,
                                              float* __restrict__ cbT) {
    int k = blockIdx.x * 256 + threadIdx.x;
    for (int c = 0; c < 256; c++) cbT[c * 1024 + k] = cb[(size_t)k * 256 + c];
}

// ---------------- np-bit-exact rescore of flagged points (8 points per block) ----------------
__global__ __launch_bounds__(256) void vq_rescue(const float* __restrict__ z,
                                                 const float* __restrict__ cbT,
                                                 const float* __restrict__ s2,
                                                 const int* __restrict__ list,
                                                 const int* __restrict__ cnt,
                                                 int* __restrict__ outIdx) {
    __shared__ float zs[8][256];
    __shared__ float S1s[8];
    __shared__ float rv[256];
    __shared__ int ri[256];
    int n = *cnt; if (n > CAP) n = CAP;
    int t = threadIdx.x;
    for (int base = blockIdx.x * 8; base < n; base += gridDim.x * 8) {
        int npts = n - base; if (npts > 8) npts = 8;
        __syncthreads();
        {   // cooperative load of up to 8 z-rows
            int pp = t >> 5, c0 = (t & 31) * 8;
            if (pp < npts) {
                int p = list[base + pp];
                int b = p >> 12, hw = p & 4095;
                const float* zp = z + ((size_t)b << 20) + hw;
#pragma unroll
                for (int j = 0; j < 8; j++) zs[pp][c0 + j] = zp[(size_t)(c0 + j) << 12];
            }
        }
        __syncthreads();
        if (t < npts) S1s[t] = np_pairwise_sq_256(zs[t]);
        __syncthreads();

        // 32 independent sequential fma chains (np/BLAS bit order: k-ascending fma)
        float d[8][4];
#pragma unroll
        for (int pp = 0; pp < 8; pp++)
#pragma unroll
            for (int q = 0; q < 4; q++) d[pp][q] = 0.f;
        for (int c = 0; c < 256; c++) {
            const float* er = cbT + c * 1024 + t;
            float e0 = er[0], e1 = er[256], e2v = er[512], e3 = er[768];
#pragma unroll
            for (int pp = 0; pp < 8; pp++) {
                float zc = zs[pp][c];
                d[pp][0] = fmaf(zc, e0, d[pp][0]);
                d[pp][1] = fmaf(zc, e1, d[pp][1]);
                d[pp][2] = fmaf(zc, e2v, d[pp][2]);
                d[pp][3] = fmaf(zc, e3, d[pp][3]);
            }
        }
        float s2v[4] = {s2[t], s2[256 + t], s2[512 + t], s2[768 + t]};

        float bv[8]; int bi[8];
#pragma unroll
        for (int pp = 0; pp < 8; pp++) {
            float v = 3.4e38f; int i0 = 0;
#pragma unroll
            for (int q = 0; q < 4; q++) {
                float dist = __fsub_rn(__fadd_rn(S1s[pp], s2v[q]), __fmul_rn(2.0f, d[pp][q]));
                if (dist < v) { v = dist; i0 = q * 256 + t; }
            }
            bv[pp] = v; bi[pp] = i0;
        }
        // per-point block argmin (first-index tie-break)
        for (int pp = 0; pp < 8; pp++) {
            if (pp >= npts) break;
            rv[t] = bv[pp]; ri[t] = bi[pp];
            __syncthreads();
            for (int sft = 128; sft > 0; sft >>= 1) {
                if (t < sft) {
                    if (rv[t + sft] < rv[t] || (rv[t + sft] == rv[t] && ri[t + sft] < ri[t])) {
                        rv[t] = rv[t + sft]; ri[t] = ri[t + sft];
                    }
                }
                __syncthreads();
            }
            if (t == 0) outIdx[list[base + pp]] = ri[0];
            __syncthreads();
        }
    }
}

// ---------------- gather z_q, write indices, partial loss ----------------
__global__ __launch_bounds__(256) void vq_gather(const float* __restrict__ z,
                                                 const float* __restrict__ cb,
                                                 const int* __restrict__ idxs,
                                                 float* __restrict__ out,
                                                 float* __restrict__ partial) {
    int tid = blockIdx.x * 256 + threadIdx.x;
    int hw = tid & 4095;
    int bg = tid >> 12;
    int b = bg >> 5, cg = bg & 31;
    int id = idxs[(b << 12) + hw];
    const float4* cr = (const float4*)(cb + (size_t)id * CDIM + cg * 8);
    float4 v0 = cr[0], v1 = cr[1];
    float va[8] = {v0.x, v0.y, v0.z, v0.w, v1.x, v1.y, v1.z, v1.w};
    size_t base = ((size_t)(b * 256 + cg * 8) << 12) + hw;
    float s = 0.f;
#pragma unroll
    for (int j = 0; j < 8; j++) {
        float ze = z[base + ((size_t)j << 12)];
        out[base + ((size_t)j << 12)] = va[j];
        float d = va[j] - ze;
        s = fmaf(d, d, s);
    }
    if (cg == 0) out[(size_t)ZQ_ELEMS + 1u + (b << 12) + hw] = (float)id;
#pragma unroll
    for (int off = 32; off > 0; off >>= 1) s += __shfl_down(s, off);
    __shared__ float red[4];
    if ((threadIdx.x & 63) == 0) red[threadIdx.x >> 6] = s;
    __syncthreads();
    if (threadIdx.x == 0) partial[blockIdx.x] = red[0] + red[1] + red[2] + red[3];
}

__global__ __launch_bounds__(512) void vq_finalize(const float* __restrict__ partial,
                                                   float* __restrict__ out) {
    int t = threadIdx.x;
    double s = 0.0;
    for (int i = t; i < 16384; i += 512) s += (double)partial[i];
#pragma unroll
    for (int off = 32; off > 0; off >>= 1) s += __shfl_down(s, off);
    __shared__ double sd[8];
    if ((t & 63) == 0) sd[t >> 6] = s;
    __syncthreads();
    if (t == 0) {
        double tot = sd[0] + sd[1] + sd[2] + sd[3] + sd[4] + sd[5] + sd[6] + sd[7];
        out[ZQ_ELEMS] = (float)(1.25 * tot / (double)ZQ_ELEMS);
    }
}

extern "C" void kernel_launch(void* const* d_in, const int* in_sizes, int n_in,
                              void* d_out, int out_size, void* d_ws, size_t ws_size,
                              hipStream_t stream) {
    const float* z = (const float*)d_in[0];        // [32,256,64,64] f32
    const float* cb = (const float*)d_in[1];       // [1024,256] f32
    unsigned char* ws = (unsigned char*)d_ws;
    unsigned char* img = ws + WS_IMG;
    float* cbT = (float*)(ws + WS_IMG);            // aliases img (dead after vq_dist)
    float* s2 = (float*)(ws + WS_S2);
    int* idx = (int*)(ws + WS_IDX);
    float* partial = (float*)(ws + WS_PART);
    int* cnt = (int*)(ws + WS_CNT);
    int* list = (int*)(ws + WS_LIST);
    float* out = (float*)d_out;

    vq_prep<<<128, 256, 0, stream>>>(cb, img, cnt);
    vq_s2prep<<<4, 256, 0, stream>>>(cb, s2);
    vq_dist<<<1024, 256, 0, stream>>>(z, img, s2, idx, cnt, list);
    vq_cbt<<<4, 256, 0, stream>>>(cb, cbT);
    vq_rescue<<<512, 256, 0, stream>>>(z, cbT, s2, list, cnt, idx);
    vq_gather<<<16384, 256, 0, stream>>>(z, cb, idx, out, partial);
    vq_finalize<<<1, 512, 0, stream>>>(partial, out);
}

// Round 11
// 372.236 us; speedup vs baseline: 1.1898x; 1.1898x over previous
//
#include <hip/hip_runtime.h>
#include <stdint.h>

typedef __attribute__((ext_vector_type(8))) _Float16 half8;
typedef __attribute__((ext_vector_type(4))) float f32x4;

#define CDIM 256
#define KCODES 1024
#define NPTS 131072
#define ZQ_ELEMS 33554432u
#define CAP 32768
#define MARGIN 3.0e-4f

// ws layout (bytes)
#define WS_IMG 0                          // 512 KiB fp16-hi fragment-major codebook image; ALIASED by cbT after vq_dist
#define WS_S2 (16 * 65536)                // 1024 floats (np-pairwise ||e||^2)
#define WS_IDX (WS_S2 + 4096)             // 131072 ints
#define WS_PART (WS_IDX + NPTS * 4)       // 16384 floats
#define WS_CNT (WS_PART + 65536)          // 1 int (+pad)
#define WS_LIST (WS_CNT + 64)             // CAP ints

// EXACT replica of numpy pairwise_sum over fl(x[c]*x[c]) for n=256 (verified round 3).
__device__ __forceinline__ float np_pairwise_sq_256(const float* x) {
    float res[2];
#pragma unroll
    for (int h = 0; h < 2; h++) {
        const float* a = x + h * 128;
        float r[8];
#pragma unroll
        for (int j = 0; j < 8; j++) r[j] = __fmul_rn(a[j], a[j]);
#pragma unroll
        for (int i = 8; i < 128; i += 8)
#pragma unroll
            for (int j = 0; j < 8; j++)
                r[j] = __fadd_rn(r[j], __fmul_rn(a[i + j], a[i + j]));
        res[h] = __fadd_rn(__fadd_rn(__fadd_rn(r[0], r[1]), __fadd_rn(r[2], r[3])),
                           __fadd_rn(__fadd_rn(r[4], r[5]), __fadd_rn(r[6], r[7])));
    }
    return __fadd_rn(res[0], res[1]);
}

// ---------------- prep: fp16-hi FRAGMENT-MAJOR codebook image + counter reset ----------
// Chunk = 32 codes = 16 KB = 16 slots of 1 KB. Slot s = ks*2 + q holds the exact 1KB one
// wave reads with one conflict-free ds_read_b128 at addr = s*1024 + lane*16:
// lane (l4,l15) = code q*16+l15, channels ks*32+l4*8 .. +8.
__global__ __launch_bounds__(256) void vq_prep(const float* __restrict__ cb,
                                               unsigned char* __restrict__ img,
                                               int* __restrict__ cnt) {
    int t = threadIdx.x;
    if (blockIdx.x == 0 && t == 0) *cnt = 0;
    int codeLocal = t >> 5;      // 0..7
    int cg = t & 31;             // 8-channel group
    int k = blockIdx.x * 8 + codeLocal;
    const float* row = cb + k * CDIM + cg * 8;
    union H { _Float16 h[8]; uint4 u; } hi;
#pragma unroll
    for (int j = 0; j < 8; j++) hi.h[j] = (_Float16)(row[j] * 1024.f);
    int chunk = k >> 5, rowi = k & 31;
    int ks = cg >> 2, l4 = cg & 3;
    int q = rowi >> 4, l15 = rowi & 15;
    int lane = l4 * 16 + l15;
    *(uint4*)(img + chunk * 16384 + ((ks * 2 + q) << 10) + lane * 16) = hi.u;
}

// ---------------- s2[k] = np-pairwise sum of codebook row squares ----------------
__global__ __launch_bounds__(256) void vq_s2prep(const float* __restrict__ cb,
                                                 float* __restrict__ s2) {
    int k = blockIdx.x * 256 + threadIdx.x;
    float e[256];
#pragma unroll
    for (int c = 0; c < 256; c++) e[c] = cb[(size_t)k * CDIM + c];
    s2[k] = np_pairwise_sq_256(e);
}

// ---------------- pass 1: 1-term fp16 MFMA distances + argmin + near-tie flagging --------
// acc = 32768 * (z_hi . e_hi); dropped z_lo/e_lo terms ~1e-5 rms, covered by MARGIN+rescue.
// Double-buffered 16KB LDS chunks, 32 chunks; ~140 VGPR -> 3 waves/SIMD, 3 blocks/CU.
__global__ __launch_bounds__(256, 3) void vq_dist(const float* __restrict__ z,
                                                  const unsigned char* __restrict__ img,
                                                  const float* __restrict__ s2g,
                                                  int* __restrict__ outIdx,
                                                  int* __restrict__ cnt,
                                                  int* __restrict__ list) {
    __shared__ __align__(16) unsigned char smem[2][16384];
    __shared__ float e2s[1024];
    int t = threadIdx.x;
    int lane = t & 63, wave = t >> 6;
    int l15 = lane & 15, l4 = lane >> 4;
    int blk0 = blockIdx.x * 128;               // block's first point (hw window aligned 128)
    int wbase = blk0 + wave * 32;
    int b = blk0 >> 12;
    int hwb0 = blk0 & 4095;
    const float* zb = z + (size_t)b * (CDIM * 4096);

    // stage codebook chunk 0 into buf0 (in flight across the whole prologue)
#pragma unroll
    for (int i = 0; i < 4; i++) {
        size_t off = (size_t)(i * 256 + t) * 16;
        __builtin_amdgcn_global_load_lds(
            (const __attribute__((address_space(1))) void*)(img + off),
            (__attribute__((address_space(3))) void*)(&smem[0][0] + off), 16, 0, 0);
    }
#pragma unroll
    for (int i = 0; i < 4; i++) e2s[t + i * 256] = s2g[t + i * 256];

    // coalesced A-tile prologue: 8 slices of [32ch x 128hw] = 16KB each via buf1
    half8 aHi[2][8];
#pragma unroll
    for (int ks = 0; ks < 8; ks++) {
        __syncthreads();   // buf1 free (previous slice's readers done)
#pragma unroll
        for (int i = 0; i < 4; i++) {
            int u = i * 256 + t;               // 16B unit
            int row = u >> 5, col4 = u & 31;   // row=local channel, 128 floats/row
            const float* gsrc = zb + (size_t)(ks * 32 + row) * 4096 + hwb0 + col4 * 4;
            __builtin_amdgcn_global_load_lds(
                (const __attribute__((address_space(1))) void*)gsrc,
                (__attribute__((address_space(3))) void*)(&smem[1][0] + (size_t)u * 16), 16, 0, 0);
        }
        __syncthreads();   // slice ready
#pragma unroll
        for (int m = 0; m < 2; m++) {
            half8 h;
#pragma unroll
            for (int j = 0; j < 8; j++) {
                float f = *(const float*)(&smem[1][0] +
                        (size_t)(((l4 * 8 + j) * 128) + wave * 32 + m * 16 + l15) * 4) * 32.f;
                h[j] = (_Float16)f;
            }
            aHi[m][ks] = h;
        }
    }
    __syncthreads();       // last slice readers done -> buf1 reusable for chunk staging

    float bestv[2][4], bestv2[2][4];
    int besti[2][4];
#pragma unroll
    for (int m = 0; m < 2; m++)
#pragma unroll
        for (int j = 0; j < 4; j++) { bestv[m][j] = 3.0e38f; bestv2[m][j] = 3.0e38f; besti[m][j] = 0; }

    int cur = 0;
    for (int chunk = 0; chunk < 32; chunk++) {
        // prefetch next chunk into the other buffer (stays in flight across compute)
        if (chunk < 31) {
            const unsigned char* src = img + (size_t)(chunk + 1) * 16384;
            unsigned char* dst = &smem[cur ^ 1][0];
#pragma unroll
            for (int i = 0; i < 4; i++) {
                size_t off = (size_t)(i * 256 + t) * 16;
                __builtin_amdgcn_global_load_lds(
                    (const __attribute__((address_space(1))) void*)(src + off),
                    (__attribute__((address_space(3))) void*)(dst + off), 16, 0, 0);
            }
        }

        f32x4 acc[2][2];
#pragma unroll
        for (int m = 0; m < 2; m++)
#pragma unroll
            for (int q = 0; q < 2; q++) acc[m][q] = (f32x4){0.f, 0.f, 0.f, 0.f};

        const unsigned char* bufc = &smem[cur][0] + lane * 16;
#pragma unroll
        for (int ks = 0; ks < 8; ks++) {
            half8 b0 = *(const half8*)(bufc + (ks << 11));
            half8 b1 = *(const half8*)(bufc + (ks << 11) + 1024);
#pragma unroll
            for (int m = 0; m < 2; m++) {
                acc[m][0] = __builtin_amdgcn_mfma_f32_16x16x32_f16(aHi[m][ks], b0, acc[m][0], 0, 0, 0);
                acc[m][1] = __builtin_amdgcn_mfma_f32_16x16x32_f16(aHi[m][ks], b1, acc[m][1], 0, 0, 0);
            }
        }
        // d' = s2 - acc/16384; track best + 2nd best
#pragma unroll
        for (int q = 0; q < 2; q++) {
            int code = chunk * 32 + q * 16 + l15;
            float ev = e2s[code];
#pragma unroll
            for (int m = 0; m < 2; m++)
#pragma unroll
                for (int j = 0; j < 4; j++) {
                    float s = fmaf(acc[m][q][j], -6.103515625e-05f, ev);
                    if (s < bestv[m][j]) { bestv2[m][j] = bestv[m][j]; bestv[m][j] = s; besti[m][j] = code; }
                    else if (s < bestv2[m][j]) bestv2[m][j] = s;
                }
        }
        __syncthreads();   // next buffer staged + all readers of bufc done
        cur ^= 1;
    }

#pragma unroll
    for (int m = 0; m < 2; m++)
#pragma unroll
        for (int j = 0; j < 4; j++) {
            float v = bestv[m][j], v2 = bestv2[m][j];
            int idx = besti[m][j];
#pragma unroll
            for (int off = 1; off < 16; off <<= 1) {
                float ov = __shfl_xor(v, off);
                float ov2 = __shfl_xor(v2, off);
                int oi = __shfl_xor(idx, off);
                if (ov < v || (ov == v && oi < idx)) { v2 = fminf(v, ov2); v = ov; idx = oi; }
                else v2 = fminf(v2, ov);
            }
            if (l15 == 0) {
                int p = wbase + m * 16 + l4 * 4 + j;
                outIdx[p] = idx;
                if (v2 - v < MARGIN) {
                    int pos = atomicAdd(cnt, 1);
                    if (pos < CAP) list[pos] = p;
                }
            }
        }
}

// ---------------- transpose codebook into cbT[256][1024] (aliases dead img region) --------
__global__ __launch_bounds__(256) void vq_cbt(const float* __restrict__ cb,
                                              float* __restrict__ cbT) {
    int k = blockIdx.x * 256 + threadIdx.x;
    for (int c = 0; c < 256; c++) cbT[c * 1024 + k] = cb[(size_t)k * 256 + c];
}

// ---------------- np-bit-exact rescore of flagged points (8 points per block) ----------------
__global__ __launch_bounds__(256) void vq_rescue(const float* __restrict__ z,
                                                 const float* __restrict__ cbT,
                                                 const float* __restrict__ s2,
                                                 const int* __restrict__ list,
                                                 const int* __restrict__ cnt,
                                                 int* __restrict__ outIdx) {
    __shared__ float zs[8][256];
    __shared__ float S1s[8];
    __shared__ float rv[256];
    __shared__ int ri[256];
    int n = *cnt; if (n > CAP) n = CAP;
    int t = threadIdx.x;
    for (int base = blockIdx.x * 8; base < n; base += gridDim.x * 8) {
        int npts = n - base; if (npts > 8) npts = 8;
        __syncthreads();
        {   // cooperative load of up to 8 z-rows
            int pp = t >> 5, c0 = (t & 31) * 8;
            if (pp < npts) {
                int p = list[base + pp];
                int b = p >> 12, hw = p & 4095;
                const float* zp = z + ((size_t)b << 20) + hw;
#pragma unroll
                for (int j = 0; j < 8; j++) zs[pp][c0 + j] = zp[(size_t)(c0 + j) << 12];
            }
        }
        __syncthreads();
        if (t < npts) S1s[t] = np_pairwise_sq_256(zs[t]);
        __syncthreads();

        // 32 independent sequential fma chains (np/BLAS bit order: k-ascending fma)
        float d[8][4];
#pragma unroll
        for (int pp = 0; pp < 8; pp++)
#pragma unroll
            for (int q = 0; q < 4; q++) d[pp][q] = 0.f;
        for (int c = 0; c < 256; c++) {
            const float* er = cbT + c * 1024 + t;
            float e0 = er[0], e1 = er[256], e2v = er[512], e3 = er[768];
#pragma unroll
            for (int pp = 0; pp < 8; pp++) {
                float zc = zs[pp][c];
                d[pp][0] = fmaf(zc, e0, d[pp][0]);
                d[pp][1] = fmaf(zc, e1, d[pp][1]);
                d[pp][2] = fmaf(zc, e2v, d[pp][2]);
                d[pp][3] = fmaf(zc, e3, d[pp][3]);
            }
        }
        float s2v[4] = {s2[t], s2[256 + t], s2[512 + t], s2[768 + t]};

        float bv[8]; int bi[8];
#pragma unroll
        for (int pp = 0; pp < 8; pp++) {
            float v = 3.4e38f; int i0 = 0;
#pragma unroll
            for (int q = 0; q < 4; q++) {
                float dist = __fsub_rn(__fadd_rn(S1s[pp], s2v[q]), __fmul_rn(2.0f, d[pp][q]));
                if (dist < v) { v = dist; i0 = q * 256 + t; }
            }
            bv[pp] = v; bi[pp] = i0;
        }
        // per-point block argmin (first-index tie-break)
        for (int pp = 0; pp < 8; pp++) {
            if (pp >= npts) break;
            rv[t] = bv[pp]; ri[t] = bi[pp];
            __syncthreads();
            for (int sft = 128; sft > 0; sft >>= 1) {
                if (t < sft) {
                    if (rv[t + sft] < rv[t] || (rv[t + sft] == rv[t] && ri[t + sft] < ri[t])) {
                        rv[t] = rv[t + sft]; ri[t] = ri[t + sft];
                    }
                }
                __syncthreads();
            }
            if (t == 0) outIdx[list[base + pp]] = ri[0];
            __syncthreads();
        }
    }
}

// ---------------- gather z_q, write indices, partial loss ----------------
__global__ __launch_bounds__(256) void vq_gather(const float* __restrict__ z,
                                                 const float* __restrict__ cb,
                                                 const int* __restrict__ idxs,
                                                 float* __restrict__ out,
                                                 float* __restrict__ partial) {
    int tid = blockIdx.x * 256 + threadIdx.x;
    int hw = tid & 4095;
    int bg = tid >> 12;
    int b = bg >> 5, cg = bg & 31;
    int id = idxs[(b << 12) + hw];
    const float4* cr = (const float4*)(cb + (size_t)id * CDIM + cg * 8);
    float4 v0 = cr[0], v1 = cr[1];
    float va[8] = {v0.x, v0.y, v0.z, v0.w, v1.x, v1.y, v1.z, v1.w};
    size_t base = ((size_t)(b * 256 + cg * 8) << 12) + hw;
    float s = 0.f;
#pragma unroll
    for (int j = 0; j < 8; j++) {
        float ze = z[base + ((size_t)j << 12)];
        out[base + ((size_t)j << 12)] = va[j];
        float d = va[j] - ze;
        s = fmaf(d, d, s);
    }
    if (cg == 0) out[(size_t)ZQ_ELEMS + 1u + (b << 12) + hw] = (float)id;
#pragma unroll
    for (int off = 32; off > 0; off >>= 1) s += __shfl_down(s, off);
    __shared__ float red[4];
    if ((threadIdx.x & 63) == 0) red[threadIdx.x >> 6] = s;
    __syncthreads();
    if (threadIdx.x == 0) partial[blockIdx.x] = red[0] + red[1] + red[2] + red[3];
}

__global__ __launch_bounds__(512) void vq_finalize(const float* __restrict__ partial,
                                                   float* __restrict__ out) {
    int t = threadIdx.x;
    double s = 0.0;
    for (int i = t; i < 16384; i += 512) s += (double)partial[i];
#pragma unroll
    for (int off = 32; off > 0; off >>= 1) s += __shfl_down(s, off);
    __shared__ double sd[8];
    if ((t & 63) == 0) sd[t >> 6] = s;
    __syncthreads();
    if (t == 0) {
        double tot = sd[0] + sd[1] + sd[2] + sd[3] + sd[4] + sd[5] + sd[6] + sd[7];
        out[ZQ_ELEMS] = (float)(1.25 * tot / (double)ZQ_ELEMS);
    }
}

extern "C" void kernel_launch(void* const* d_in, const int* in_sizes, int n_in,
                              void* d_out, int out_size, void* d_ws, size_t ws_size,
                              hipStream_t stream) {
    const float* z = (const float*)d_in[0];        // [32,256,64,64] f32
    const float* cb = (const float*)d_in[1];       // [1024,256] f32
    unsigned char* ws = (unsigned char*)d_ws;
    unsigned char* img = ws + WS_IMG;
    float* cbT = (float*)(ws + WS_IMG);            // aliases img (dead after vq_dist)
    float* s2 = (float*)(ws + WS_S2);
    int* idx = (int*)(ws + WS_IDX);
    float* partial = (float*)(ws + WS_PART);
    int* cnt = (int*)(ws + WS_CNT);
    int* list = (int*)(ws + WS_LIST);
    float* out = (float*)d_out;

    vq_prep<<<128, 256, 0, stream>>>(cb, img, cnt);
    vq_s2prep<<<4, 256, 0, stream>>>(cb, s2);
    vq_dist<<<1024, 256, 0, stream>>>(z, img, s2, idx, cnt, list);
    vq_cbt<<<4, 256, 0, stream>>>(cb, cbT);
    vq_rescue<<<512, 256, 0, stream>>>(z, cbT, s2, list, cnt, idx);
    vq_gather<<<16384, 256, 0, stream>>>(z, cb, idx, out, partial);
    vq_finalize<<<1, 512, 0, stream>>>(partial, out);
}

// Round 12
// 362.872 us; speedup vs baseline: 1.2205x; 1.0258x over previous
//
#include <hip/hip_runtime.h>
#include <stdint.h>

typedef __attribute__((ext_vector_type(8))) _Float16 half8;
typedef __attribute__((ext_vector_type(4))) float f32x4;

#define CDIM 256
#define KCODES 1024
#define NPTS 131072
#define ZQ_ELEMS 33554432u
#define CAP 32768
#define MARGIN 3.0e-4f

// ws layout (bytes)
#define WS_IMG 0                          // 512 KiB fp16-hi fragment-major codebook image; ALIASED by cbT after vq_dist
#define WS_S2 (16 * 65536)                // 1024 floats (np-pairwise ||e||^2)
#define WS_IDX (WS_S2 + 4096)             // 131072 ints
#define WS_PART (WS_IDX + NPTS * 4)       // 16384 floats
#define WS_CNT (WS_PART + 65536)          // 1 int (+pad)
#define WS_LIST (WS_CNT + 64)             // CAP ints

// EXACT replica of numpy pairwise_sum over fl(x[c]*x[c]) for n=256 (verified round 3).
__device__ __forceinline__ float np_pairwise_sq_256(const float* x) {
    float res[2];
#pragma unroll
    for (int h = 0; h < 2; h++) {
        const float* a = x + h * 128;
        float r[8];
#pragma unroll
        for (int j = 0; j < 8; j++) r[j] = __fmul_rn(a[j], a[j]);
#pragma unroll
        for (int i = 8; i < 128; i += 8)
#pragma unroll
            for (int j = 0; j < 8; j++)
                r[j] = __fadd_rn(r[j], __fmul_rn(a[i + j], a[i + j]));
        res[h] = __fadd_rn(__fadd_rn(__fadd_rn(r[0], r[1]), __fadd_rn(r[2], r[3])),
                           __fadd_rn(__fadd_rn(r[4], r[5]), __fadd_rn(r[6], r[7])));
    }
    return __fadd_rn(res[0], res[1]);
}

// ---------------- prep: fp16-hi FRAGMENT-MAJOR codebook image + counter reset ----------
// Chunk = 32 codes = 16 KB = 16 slots of 1 KB. Slot s = ks*2 + q holds the exact 1KB one
// wave reads with one conflict-free ds_read_b128 at addr = s*1024 + lane*16:
// lane (l4,l15) = code q*16+l15, channels ks*32+l4*8 .. +8.
__global__ __launch_bounds__(256) void vq_prep(const float* __restrict__ cb,
                                               unsigned char* __restrict__ img,
                                               int* __restrict__ cnt) {
    int t = threadIdx.x;
    if (blockIdx.x == 0 && t == 0) *cnt = 0;
    int codeLocal = t >> 5;      // 0..7
    int cg = t & 31;             // 8-channel group
    int k = blockIdx.x * 8 + codeLocal;
    const float* row = cb + k * CDIM + cg * 8;
    union H { _Float16 h[8]; uint4 u; } hi;
#pragma unroll
    for (int j = 0; j < 8; j++) hi.h[j] = (_Float16)(row[j] * 1024.f);
    int chunk = k >> 5, rowi = k & 31;
    int ks = cg >> 2, l4 = cg & 3;
    int q = rowi >> 4, l15 = rowi & 15;
    int lane = l4 * 16 + l15;
    *(uint4*)(img + chunk * 16384 + ((ks * 2 + q) << 10) + lane * 16) = hi.u;
}

// ---------------- s2[k] = np-pairwise sum of codebook row squares ----------------
__global__ __launch_bounds__(256) void vq_s2prep(const float* __restrict__ cb,
                                                 float* __restrict__ s2) {
    int k = blockIdx.x * 256 + threadIdx.x;
    float e[256];
#pragma unroll
    for (int c = 0; c < 256; c++) e[c] = cb[(size_t)k * CDIM + c];
    s2[k] = np_pairwise_sq_256(e);
}

// ---------------- pass 1: 1-term fp16 MFMA, M_rep=4 (64 pts/wave, 256 pts/block) --------
// 64 MFMA per wave per chunk between barriers; 512 blocks, 2 blocks/CU.
__global__ __launch_bounds__(256, 2) void vq_dist(const float* __restrict__ z,
                                                  const unsigned char* __restrict__ img,
                                                  const float* __restrict__ s2g,
                                                  int* __restrict__ outIdx,
                                                  int* __restrict__ cnt,
                                                  int* __restrict__ list) {
    __shared__ __align__(16) unsigned char smem[2][16384];
    __shared__ float e2s[1024];
    int t = threadIdx.x;
    int lane = t & 63, wave = t >> 6;
    int l15 = lane & 15, l4 = lane >> 4;
    int blk0 = blockIdx.x * 256;               // block's first point (256-aligned hw window)
    int wbase = blk0 + wave * 64;
    int b = blk0 >> 12;
    int hwb0 = blk0 & 4095;
    const float* zb = z + (size_t)b * (CDIM * 4096);
    unsigned char* sbase = &smem[0][0];        // 32KB combined staging region (prologue)

#pragma unroll
    for (int i = 0; i < 4; i++) e2s[t + i * 256] = s2g[t + i * 256];

    // coalesced A-tile prologue: 8 slices of [32ch x 256hw] = 32KB via combined buffers
    half8 aHi[4][8];
#pragma unroll
    for (int ks = 0; ks < 8; ks++) {
        __syncthreads();   // staging region free (previous slice's readers done)
#pragma unroll
        for (int i = 0; i < 8; i++) {
            int u = i * 256 + t;               // 16B unit; 2048 units = 32KB
            int row = u >> 6, col16 = u & 63;  // row=local channel, 256 floats/row
            const float* gsrc = zb + (size_t)(ks * 32 + row) * 4096 + hwb0 + col16 * 4;
            __builtin_amdgcn_global_load_lds(
                (const __attribute__((address_space(1))) void*)gsrc,
                (__attribute__((address_space(3))) void*)(sbase + (size_t)u * 16), 16, 0, 0);
        }
        __syncthreads();   // slice ready
#pragma unroll
        for (int m = 0; m < 4; m++) {
            half8 h;
#pragma unroll
            for (int j = 0; j < 8; j++) {
                float f = *(const float*)(sbase +
                        (size_t)(((l4 * 8 + j) << 8) + wave * 64 + m * 16 + l15) * 4) * 32.f;
                h[j] = (_Float16)f;
            }
            aHi[m][ks] = h;
        }
    }
    __syncthreads();       // prologue done; stage codebook chunk 0 into buf0
#pragma unroll
    for (int i = 0; i < 4; i++) {
        size_t off = (size_t)(i * 256 + t) * 16;
        __builtin_amdgcn_global_load_lds(
            (const __attribute__((address_space(1))) void*)(img + off),
            (__attribute__((address_space(3))) void*)(&smem[0][0] + off), 16, 0, 0);
    }
    __syncthreads();       // chunk 0 staged

    float bestv[4][4], bestv2[4][4];
    int besti[4][4];
#pragma unroll
    for (int m = 0; m < 4; m++)
#pragma unroll
        for (int j = 0; j < 4; j++) { bestv[m][j] = 3.0e38f; bestv2[m][j] = 3.0e38f; besti[m][j] = 0; }

    int cur = 0;
    for (int chunk = 0; chunk < 32; chunk++) {
        // prefetch next chunk into the other buffer (stays in flight across compute)
        if (chunk < 31) {
            const unsigned char* src = img + (size_t)(chunk + 1) * 16384;
            unsigned char* dst = &smem[cur ^ 1][0];
#pragma unroll
            for (int i = 0; i < 4; i++) {
                size_t off = (size_t)(i * 256 + t) * 16;
                __builtin_amdgcn_global_load_lds(
                    (const __attribute__((address_space(1))) void*)(src + off),
                    (__attribute__((address_space(3))) void*)(dst + off), 16, 0, 0);
            }
        }

        f32x4 acc[4][2];
#pragma unroll
        for (int m = 0; m < 4; m++)
#pragma unroll
            for (int q = 0; q < 2; q++) acc[m][q] = (f32x4){0.f, 0.f, 0.f, 0.f};

        const unsigned char* bufc = &smem[cur][0] + lane * 16;
#pragma unroll
        for (int ks = 0; ks < 8; ks++) {
            half8 b0 = *(const half8*)(bufc + (ks << 11));
            half8 b1 = *(const half8*)(bufc + (ks << 11) + 1024);
#pragma unroll
            for (int m = 0; m < 4; m++) {
                acc[m][0] = __builtin_amdgcn_mfma_f32_16x16x32_f16(aHi[m][ks], b0, acc[m][0], 0, 0, 0);
                acc[m][1] = __builtin_amdgcn_mfma_f32_16x16x32_f16(aHi[m][ks], b1, acc[m][1], 0, 0, 0);
            }
        }
        // d' = s2 - acc/16384; track best + 2nd best
#pragma unroll
        for (int q = 0; q < 2; q++) {
            int code = chunk * 32 + q * 16 + l15;
            float ev = e2s[code];
#pragma unroll
            for (int m = 0; m < 4; m++)
#pragma unroll
                for (int j = 0; j < 4; j++) {
                    float s = fmaf(acc[m][q][j], -6.103515625e-05f, ev);
                    if (s < bestv[m][j]) { bestv2[m][j] = bestv[m][j]; bestv[m][j] = s; besti[m][j] = code; }
                    else if (s < bestv2[m][j]) bestv2[m][j] = s;
                }
        }
        __syncthreads();   // next buffer staged + all readers of bufc done
        cur ^= 1;
    }

#pragma unroll
    for (int m = 0; m < 4; m++)
#pragma unroll
        for (int j = 0; j < 4; j++) {
            float v = bestv[m][j], v2 = bestv2[m][j];
            int idx = besti[m][j];
#pragma unroll
            for (int off = 1; off < 16; off <<= 1) {
                float ov = __shfl_xor(v, off);
                float ov2 = __shfl_xor(v2, off);
                int oi = __shfl_xor(idx, off);
                if (ov < v || (ov == v && oi < idx)) { v2 = fminf(v, ov2); v = ov; idx = oi; }
                else v2 = fminf(v2, ov);
            }
            if (l15 == 0) {
                int p = wbase + m * 16 + l4 * 4 + j;
                outIdx[p] = idx;
                if (v2 - v < MARGIN) {
                    int pos = atomicAdd(cnt, 1);
                    if (pos < CAP) list[pos] = p;
                }
            }
        }
}

// ---------------- transpose codebook into cbT[256][1024] (aliases dead img region) --------
__global__ __launch_bounds__(256) void vq_cbt(const float* __restrict__ cb,
                                              float* __restrict__ cbT) {
    int k = blockIdx.x * 256 + threadIdx.x;
    for (int c = 0; c < 256; c++) cbT[c * 1024 + k] = cb[(size_t)k * 256 + c];
}

// ---------------- np-bit-exact rescore of flagged points (8 points per block) ----------------
__global__ __launch_bounds__(256) void vq_rescue(const float* __restrict__ z,
                                                 const float* __restrict__ cbT,
                                                 const float* __restrict__ s2,
                                                 const int* __restrict__ list,
                                                 const int* __restrict__ cnt,
                                                 int* __restrict__ outIdx) {
    __shared__ float zs[8][256];
    __shared__ float S1s[8];
    __shared__ float rv[256];
    __shared__ int ri[256];
    int n = *cnt; if (n > CAP) n = CAP;
    int t = threadIdx.x;
    for (int base = blockIdx.x * 8; base < n; base += gridDim.x * 8) {
        int npts = n - base; if (npts > 8) npts = 8;
        __syncthreads();
        {   // cooperative load of up to 8 z-rows
            int pp = t >> 5, c0 = (t & 31) * 8;
            if (pp < npts) {
                int p = list[base + pp];
                int b = p >> 12, hw = p & 4095;
                const float* zp = z + ((size_t)b << 20) + hw;
#pragma unroll
                for (int j = 0; j < 8; j++) zs[pp][c0 + j] = zp[(size_t)(c0 + j) << 12];
            }
        }
        __syncthreads();
        if (t < npts) S1s[t] = np_pairwise_sq_256(zs[t]);
        __syncthreads();

        // 32 independent sequential fma chains (np/BLAS bit order: k-ascending fma)
        float d[8][4];
#pragma unroll
        for (int pp = 0; pp < 8; pp++)
#pragma unroll
            for (int q = 0; q < 4; q++) d[pp][q] = 0.f;
        for (int c = 0; c < 256; c++) {
            const float* er = cbT + c * 1024 + t;
            float e0 = er[0], e1 = er[256], e2v = er[512], e3 = er[768];
#pragma unroll
            for (int pp = 0; pp < 8; pp++) {
                float zc = zs[pp][c];
                d[pp][0] = fmaf(zc, e0, d[pp][0]);
                d[pp][1] = fmaf(zc, e1, d[pp][1]);
                d[pp][2] = fmaf(zc, e2v, d[pp][2]);
                d[pp][3] = fmaf(zc, e3, d[pp][3]);
            }
        }
        float s2v[4] = {s2[t], s2[256 + t], s2[512 + t], s2[768 + t]};

        float bv[8]; int bi[8];
#pragma unroll
        for (int pp = 0; pp < 8; pp++) {
            float v = 3.4e38f; int i0 = 0;
#pragma unroll
            for (int q = 0; q < 4; q++) {
                float dist = __fsub_rn(__fadd_rn(S1s[pp], s2v[q]), __fmul_rn(2.0f, d[pp][q]));
                if (dist < v) { v = dist; i0 = q * 256 + t; }
            }
            bv[pp] = v; bi[pp] = i0;
        }
        // per-point block argmin (first-index tie-break)
        for (int pp = 0; pp < 8; pp++) {
            if (pp >= npts) break;
            rv[t] = bv[pp]; ri[t] = bi[pp];
            __syncthreads();
            for (int sft = 128; sft > 0; sft >>= 1) {
                if (t < sft) {
                    if (rv[t + sft] < rv[t] || (rv[t + sft] == rv[t] && ri[t + sft] < ri[t])) {
                        rv[t] = rv[t + sft]; ri[t] = ri[t + sft];
                    }
                }
                __syncthreads();
            }
            if (t == 0) outIdx[list[base + pp]] = ri[0];
            __syncthreads();
        }
    }
}

// ---------------- gather z_q, write indices, partial loss ----------------
__global__ __launch_bounds__(256) void vq_gather(const float* __restrict__ z,
                                                 const float* __restrict__ cb,
                                                 const int* __restrict__ idxs,
                                                 float* __restrict__ out,
                                                 float* __restrict__ partial) {
    int tid = blockIdx.x * 256 + threadIdx.x;
    int hw = tid & 4095;
    int bg = tid >> 12;
    int b = bg >> 5, cg = bg & 31;
    int id = idxs[(b << 12) + hw];
    const float4* cr = (const float4*)(cb + (size_t)id * CDIM + cg * 8);
    float4 v0 = cr[0], v1 = cr[1];
    float va[8] = {v0.x, v0.y, v0.z, v0.w, v1.x, v1.y, v1.z, v1.w};
    size_t base = ((size_t)(b * 256 + cg * 8) << 12) + hw;
    float s = 0.f;
#pragma unroll
    for (int j = 0; j < 8; j++) {
        float ze = z[base + ((size_t)j << 12)];
        out[base + ((size_t)j << 12)] = va[j];
        float d = va[j] - ze;
        s = fmaf(d, d, s);
    }
    if (cg == 0) out[(size_t)ZQ_ELEMS + 1u + (b << 12) + hw] = (float)id;
#pragma unroll
    for (int off = 32; off > 0; off >>= 1) s += __shfl_down(s, off);
    __shared__ float red[4];
    if ((threadIdx.x & 63) == 0) red[threadIdx.x >> 6] = s;
    __syncthreads();
    if (threadIdx.x == 0) partial[blockIdx.x] = red[0] + red[1] + red[2] + red[3];
}

__global__ __launch_bounds__(512) void vq_finalize(const float* __restrict__ partial,
                                                   float* __restrict__ out) {
    int t = threadIdx.x;
    double s = 0.0;
    for (int i = t; i < 16384; i += 512) s += (double)partial[i];
#pragma unroll
    for (int off = 32; off > 0; off >>= 1) s += __shfl_down(s, off);
    __shared__ double sd[8];
    if ((t & 63) == 0) sd[t >> 6] = s;
    __syncthreads();
    if (t == 0) {
        double tot = sd[0] + sd[1] + sd[2] + sd[3] + sd[4] + sd[5] + sd[6] + sd[7];
        out[ZQ_ELEMS] = (float)(1.25 * tot / (double)ZQ_ELEMS);
    }
}

extern "C" void kernel_launch(void* const* d_in, const int* in_sizes, int n_in,
                              void* d_out, int out_size, void* d_ws, size_t ws_size,
                              hipStream_t stream) {
    const float* z = (const float*)d_in[0];        // [32,256,64,64] f32
    const float* cb = (const float*)d_in[1];       // [1024,256] f32
    unsigned char* ws = (unsigned char*)d_ws;
    unsigned char* img = ws + WS_IMG;
    float* cbT = (float*)(ws + WS_IMG);            // aliases img (dead after vq_dist)
    float* s2 = (float*)(ws + WS_S2);
    int* idx = (int*)(ws + WS_IDX);
    float* partial = (float*)(ws + WS_PART);
    int* cnt = (int*)(ws + WS_CNT);
    int* list = (int*)(ws + WS_LIST);
    float* out = (float*)d_out;

    vq_prep<<<128, 256, 0, stream>>>(cb, img, cnt);
    vq_s2prep<<<4, 256, 0, stream>>>(cb, s2);
    vq_dist<<<512, 256, 0, stream>>>(z, img, s2, idx, cnt, list);
    vq_cbt<<<4, 256, 0, stream>>>(cb, cbT);
    vq_rescue<<<512, 256, 0, stream>>>(z, cbT, s2, list, cnt, idx);
    vq_gather<<<16384, 256, 0, stream>>>(z, cb, idx, out, partial);
    vq_finalize<<<1, 512, 0, stream>>>(partial, out);
}

// Round 13
// 361.627 us; speedup vs baseline: 1.2247x; 1.0034x over previous
//
#include <hip/hip_runtime.h>
#include <stdint.h>

typedef __attribute__((ext_vector_type(8))) _Float16 half8;
typedef __attribute__((ext_vector_type(4))) float f32x4;

#define CDIM 256
#define KCODES 1024
#define NPTS 131072
#define ZQ_ELEMS 33554432u
#define CAP 32768
#define MARGIN 3.0e-4f

// ws layout (bytes)
#define WS_IMG 0                          // 512 KiB fp16-hi fragment-major codebook image; ALIASED by cbT after vq_dist
#define WS_S2 (16 * 65536)                // 1024 floats (np-pairwise ||e||^2)
#define WS_IDX (WS_S2 + 4096)             // 131072 ints
#define WS_PART (WS_IDX + NPTS * 4)       // 16384 floats
#define WS_CNT (WS_PART + 65536)          // 1 int (+pad)
#define WS_LIST (WS_CNT + 64)             // CAP ints

// EXACT replica of numpy pairwise_sum over fl(x[c]*x[c]) for n=256 (verified round 3).
__device__ __forceinline__ float np_pairwise_sq_256(const float* x) {
    float res[2];
#pragma unroll
    for (int h = 0; h < 2; h++) {
        const float* a = x + h * 128;
        float r[8];
#pragma unroll
        for (int j = 0; j < 8; j++) r[j] = __fmul_rn(a[j], a[j]);
#pragma unroll
        for (int i = 8; i < 128; i += 8)
#pragma unroll
            for (int j = 0; j < 8; j++)
                r[j] = __fadd_rn(r[j], __fmul_rn(a[i + j], a[i + j]));
        res[h] = __fadd_rn(__fadd_rn(__fadd_rn(r[0], r[1]), __fadd_rn(r[2], r[3])),
                           __fadd_rn(__fadd_rn(r[4], r[5]), __fadd_rn(r[6], r[7])));
    }
    return __fadd_rn(res[0], res[1]);
}

// ---------------- prep: fp16-hi FRAGMENT-MAJOR codebook image + counter reset ----------
// Chunk = 32 codes = 16 KB = 16 slots of 1 KB. Slot s = ks*2 + q holds the exact 1KB one
// wave reads with one conflict-free ds_read_b128 at addr = s*1024 + lane*16.
__global__ __launch_bounds__(256) void vq_prep(const float* __restrict__ cb,
                                               unsigned char* __restrict__ img,
                                               int* __restrict__ cnt) {
    int t = threadIdx.x;
    if (blockIdx.x == 0 && t == 0) *cnt = 0;
    int codeLocal = t >> 5;      // 0..7
    int cg = t & 31;             // 8-channel group
    int k = blockIdx.x * 8 + codeLocal;
    const float* row = cb + k * CDIM + cg * 8;
    union H { _Float16 h[8]; uint4 u; } hi;
#pragma unroll
    for (int j = 0; j < 8; j++) hi.h[j] = (_Float16)(row[j] * 1024.f);
    int chunk = k >> 5, rowi = k & 31;
    int ks = cg >> 2, l4 = cg & 3;
    int q = rowi >> 4, l15 = rowi & 15;
    int lane = l4 * 16 + l15;
    *(uint4*)(img + chunk * 16384 + ((ks * 2 + q) << 10) + lane * 16) = hi.u;
}

// ---------------- s2[k] = np-pairwise sum of codebook row squares ----------------
__global__ __launch_bounds__(256) void vq_s2prep(const float* __restrict__ cb,
                                                 float* __restrict__ s2) {
    int k = blockIdx.x * 256 + threadIdx.x;
    float e[256];
#pragma unroll
    for (int c = 0; c < 256; c++) e[c] = cb[(size_t)k * CDIM + c];
    s2[k] = np_pairwise_sq_256(e);
}

// ---------------- pass 1: 1-term fp16 MFMA, M_rep=4, COUNTED-VMCNT triple-buffer --------
// T4 port (m218/m233): raw s_barrier + s_waitcnt vmcnt(4) per chunk — prefetch loads span
// chunk boundaries; no vmcnt(0) drain in the K-loop.
__global__ __launch_bounds__(256, 2) void vq_dist(const float* __restrict__ z,
                                                  const unsigned char* __restrict__ img,
                                                  const float* __restrict__ s2g,
                                                  int* __restrict__ outIdx,
                                                  int* __restrict__ cnt,
                                                  int* __restrict__ list) {
    __shared__ __align__(16) unsigned char smem[3][16384];
    __shared__ float e2s[1024];
    int t = threadIdx.x;
    int lane = t & 63, wave = t >> 6;
    int l15 = lane & 15, l4 = lane >> 4;
    int blk0 = blockIdx.x * 256;               // block's first point (256-aligned hw window)
    int wbase = blk0 + wave * 64;
    int b = blk0 >> 12;
    int hwb0 = blk0 & 4095;
    const float* zb = z + (size_t)b * (CDIM * 4096);
    unsigned char* sbase = &smem[0][0];        // 32KB staging region (prologue, bufs 0-1)

#pragma unroll
    for (int i = 0; i < 4; i++) e2s[t + i * 256] = s2g[t + i * 256];

    // coalesced A-tile prologue: 8 slices of [32ch x 256hw] = 32KB via combined buffers
    half8 aHi[4][8];
#pragma unroll
    for (int ks = 0; ks < 8; ks++) {
        __syncthreads();   // staging region free (previous slice's readers done)
#pragma unroll
        for (int i = 0; i < 8; i++) {
            int u = i * 256 + t;               // 16B unit; 2048 units = 32KB
            int row = u >> 6, col16 = u & 63;  // row=local channel, 256 floats/row
            const float* gsrc = zb + (size_t)(ks * 32 + row) * 4096 + hwb0 + col16 * 4;
            __builtin_amdgcn_global_load_lds(
                (const __attribute__((address_space(1))) void*)gsrc,
                (__attribute__((address_space(3))) void*)(sbase + (size_t)u * 16), 16, 0, 0);
        }
        __syncthreads();   // slice ready
#pragma unroll
        for (int m = 0; m < 4; m++) {
            half8 h;
#pragma unroll
            for (int j = 0; j < 8; j++) {
                float f = *(const float*)(sbase +
                        (size_t)(((l4 * 8 + j) << 8) + wave * 64 + m * 16 + l15) * 4) * 32.f;
                h[j] = (_Float16)f;
            }
            aHi[m][ks] = h;
        }
    }
    __syncthreads();       // prologue readers done -> buffers reusable for chunk staging

    // prefetch chunks 0 and 1 (4 loads/thread each); NO drain — counted waits in the loop
#pragma unroll
    for (int i = 0; i < 4; i++) {
        size_t off = (size_t)(i * 256 + t) * 16;
        __builtin_amdgcn_global_load_lds(
            (const __attribute__((address_space(1))) void*)(img + off),
            (__attribute__((address_space(3))) void*)(&smem[0][0] + off), 16, 0, 0);
    }
#pragma unroll
    for (int i = 0; i < 4; i++) {
        size_t off = (size_t)(i * 256 + t) * 16;
        __builtin_amdgcn_global_load_lds(
            (const __attribute__((address_space(1))) void*)(img + 16384 + off),
            (__attribute__((address_space(3))) void*)(&smem[1][0] + off), 16, 0, 0);
    }

    float bestv[4][4], bestv2[4][4];
    int besti[4][4];
#pragma unroll
    for (int m = 0; m < 4; m++)
#pragma unroll
        for (int j = 0; j < 4; j++) { bestv[m][j] = 3.0e38f; bestv2[m][j] = 3.0e38f; besti[m][j] = 0; }

    int i0 = 0, i1 = 1, i2 = 2;   // rotating buffer ids: compute i0, in-flight i1, stage into i2
    for (int chunk = 0; chunk < 32; chunk++) {
        // counted wait: all but the newest 4 loads (chunk+1's) complete => chunk's buffer ready
        if (chunk < 31) asm volatile("s_waitcnt vmcnt(4)" ::: "memory");
        else            asm volatile("s_waitcnt vmcnt(0)" ::: "memory");
        __builtin_amdgcn_s_barrier();   // raw barrier: no compiler vmcnt(0) drain

        if (chunk + 2 < 32) {           // issue next-next stage; stays in flight across compute
            const unsigned char* src = img + (size_t)(chunk + 2) * 16384;
            unsigned char* dst = &smem[0][0] + (size_t)i2 * 16384;
#pragma unroll
            for (int i = 0; i < 4; i++) {
                size_t off = (size_t)(i * 256 + t) * 16;
                __builtin_amdgcn_global_load_lds(
                    (const __attribute__((address_space(1))) void*)(src + off),
                    (__attribute__((address_space(3))) void*)(dst + off), 16, 0, 0);
            }
        }

        f32x4 acc[4][2];
#pragma unroll
        for (int m = 0; m < 4; m++)
#pragma unroll
            for (int q = 0; q < 2; q++) acc[m][q] = (f32x4){0.f, 0.f, 0.f, 0.f};

        const unsigned char* bufc = &smem[0][0] + (size_t)i0 * 16384 + lane * 16;
#pragma unroll
        for (int ks = 0; ks < 8; ks++) {
            half8 b0 = *(const half8*)(bufc + (ks << 11));
            half8 b1 = *(const half8*)(bufc + (ks << 11) + 1024);
#pragma unroll
            for (int m = 0; m < 4; m++) {
                acc[m][0] = __builtin_amdgcn_mfma_f32_16x16x32_f16(aHi[m][ks], b0, acc[m][0], 0, 0, 0);
                acc[m][1] = __builtin_amdgcn_mfma_f32_16x16x32_f16(aHi[m][ks], b1, acc[m][1], 0, 0, 0);
            }
        }
        // d' = s2 - acc/16384; track best + 2nd best
#pragma unroll
        for (int q = 0; q < 2; q++) {
            int code = chunk * 32 + q * 16 + l15;
            float ev = e2s[code];
#pragma unroll
            for (int m = 0; m < 4; m++)
#pragma unroll
                for (int j = 0; j < 4; j++) {
                    float s = fmaf(acc[m][q][j], -6.103515625e-05f, ev);
                    if (s < bestv[m][j]) { bestv2[m][j] = bestv[m][j]; bestv[m][j] = s; besti[m][j] = code; }
                    else if (s < bestv2[m][j]) bestv2[m][j] = s;
                }
        }
        int tmp = i0; i0 = i1; i1 = i2; i2 = tmp;   // rotate buffers (no barrier here)
    }

#pragma unroll
    for (int m = 0; m < 4; m++)
#pragma unroll
        for (int j = 0; j < 4; j++) {
            float v = bestv[m][j], v2 = bestv2[m][j];
            int idx = besti[m][j];
#pragma unroll
            for (int off = 1; off < 16; off <<= 1) {
                float ov = __shfl_xor(v, off);
                float ov2 = __shfl_xor(v2, off);
                int oi = __shfl_xor(idx, off);
                if (ov < v || (ov == v && oi < idx)) { v2 = fminf(v, ov2); v = ov; idx = oi; }
                else v2 = fminf(v2, ov);
            }
            if (l15 == 0) {
                int p = wbase + m * 16 + l4 * 4 + j;
                outIdx[p] = idx;
                if (v2 - v < MARGIN) {
                    int pos = atomicAdd(cnt, 1);
                    if (pos < CAP) list[pos] = p;
                }
            }
        }
}

// ---------------- transpose codebook into cbT[256][1024] (aliases dead img region) --------
__global__ __launch_bounds__(256) void vq_cbt(const float* __restrict__ cb,
                                              float* __restrict__ cbT) {
    int k = blockIdx.x * 256 + threadIdx.x;
    for (int c = 0; c < 256; c++) cbT[c * 1024 + k] = cb[(size_t)k * 256 + c];
}

// ---------------- np-bit-exact rescore of flagged points (8 points per block) ----------------
__global__ __launch_bounds__(256) void vq_rescue(const float* __restrict__ z,
                                                 const float* __restrict__ cbT,
                                                 const float* __restrict__ s2,
                                                 const int* __restrict__ list,
                                                 const int* __restrict__ cnt,
                                                 int* __restrict__ outIdx) {
    __shared__ float zs[8][256];
    __shared__ float S1s[8];
    __shared__ float rv[256];
    __shared__ int ri[256];
    int n = *cnt; if (n > CAP) n = CAP;
    int t = threadIdx.x;
    for (int base = blockIdx.x * 8; base < n; base += gridDim.x * 8) {
        int npts = n - base; if (npts > 8) npts = 8;
        __syncthreads();
        {   // cooperative load of up to 8 z-rows
            int pp = t >> 5, c0 = (t & 31) * 8;
            if (pp < npts) {
                int p = list[base + pp];
                int b = p >> 12, hw = p & 4095;
                const float* zp = z + ((size_t)b << 20) + hw;
#pragma unroll
                for (int j = 0; j < 8; j++) zs[pp][c0 + j] = zp[(size_t)(c0 + j) << 12];
            }
        }
        __syncthreads();
        if (t < npts) S1s[t] = np_pairwise_sq_256(zs[t]);
        __syncthreads();

        // 32 independent sequential fma chains (np/BLAS bit order: k-ascending fma)
        float d[8][4];
#pragma unroll
        for (int pp = 0; pp < 8; pp++)
#pragma unroll
            for (int q = 0; q < 4; q++) d[pp][q] = 0.f;
        for (int c = 0; c < 256; c++) {
            const float* er = cbT + c * 1024 + t;
            float e0 = er[0], e1 = er[256], e2v = er[512], e3 = er[768];
#pragma unroll
            for (int pp = 0; pp < 8; pp++) {
                float zc = zs[pp][c];
                d[pp][0] = fmaf(zc, e0, d[pp][0]);
                d[pp][1] = fmaf(zc, e1, d[pp][1]);
                d[pp][2] = fmaf(zc, e2v, d[pp][2]);
                d[pp][3] = fmaf(zc, e3, d[pp][3]);
            }
        }
        float s2v[4] = {s2[t], s2[256 + t], s2[512 + t], s2[768 + t]};

        float bv[8]; int bi[8];
#pragma unroll
        for (int pp = 0; pp < 8; pp++) {
            float v = 3.4e38f; int i0 = 0;
#pragma unroll
            for (int q = 0; q < 4; q++) {
                float dist = __fsub_rn(__fadd_rn(S1s[pp], s2v[q]), __fmul_rn(2.0f, d[pp][q]));
                if (dist < v) { v = dist; i0 = q * 256 + t; }
            }
            bv[pp] = v; bi[pp] = i0;
        }
        // per-point block argmin (first-index tie-break)
        for (int pp = 0; pp < 8; pp++) {
            if (pp >= npts) break;
            rv[t] = bv[pp]; ri[t] = bi[pp];
            __syncthreads();
            for (int sft = 128; sft > 0; sft >>= 1) {
                if (t < sft) {
                    if (rv[t + sft] < rv[t] || (rv[t + sft] == rv[t] && ri[t + sft] < ri[t])) {
                        rv[t] = rv[t + sft]; ri[t] = ri[t + sft];
                    }
                }
                __syncthreads();
            }
            if (t == 0) outIdx[list[base + pp]] = ri[0];
            __syncthreads();
        }
    }
}

// ---------------- gather z_q, write indices, partial loss ----------------
__global__ __launch_bounds__(256) void vq_gather(const float* __restrict__ z,
                                                 const float* __restrict__ cb,
                                                 const int* __restrict__ idxs,
                                                 float* __restrict__ out,
                                                 float* __restrict__ partial) {
    int tid = blockIdx.x * 256 + threadIdx.x;
    int hw = tid & 4095;
    int bg = tid >> 12;
    int b = bg >> 5, cg = bg & 31;
    int id = idxs[(b << 12) + hw];
    const float4* cr = (const float4*)(cb + (size_t)id * CDIM + cg * 8);
    float4 v0 = cr[0], v1 = cr[1];
    float va[8] = {v0.x, v0.y, v0.z, v0.w, v1.x, v1.y, v1.z, v1.w};
    size_t base = ((size_t)(b * 256 + cg * 8) << 12) + hw;
    float s = 0.f;
#pragma unroll
    for (int j = 0; j < 8; j++) {
        float ze = z[base + ((size_t)j << 12)];
        out[base + ((size_t)j << 12)] = va[j];
        float d = va[j] - ze;
        s = fmaf(d, d, s);
    }
    if (cg == 0) out[(size_t)ZQ_ELEMS + 1u + (b << 12) + hw] = (float)id;
#pragma unroll
    for (int off = 32; off > 0; off >>= 1) s += __shfl_down(s, off);
    __shared__ float red[4];
    if ((threadIdx.x & 63) == 0) red[threadIdx.x >> 6] = s;
    __syncthreads();
    if (threadIdx.x == 0) partial[blockIdx.x] = red[0] + red[1] + red[2] + red[3];
}

__global__ __launch_bounds__(512) void vq_finalize(const float* __restrict__ partial,
                                                   float* __restrict__ out) {
    int t = threadIdx.x;
    double s = 0.0;
    for (int i = t; i < 16384; i += 512) s += (double)partial[i];
#pragma unroll
    for (int off = 32; off > 0; off >>= 1) s += __shfl_down(s, off);
    __shared__ double sd[8];
    if ((t & 63) == 0) sd[t >> 6] = s;
    __syncthreads();
    if (t == 0) {
        double tot = sd[0] + sd[1] + sd[2] + sd[3] + sd[4] + sd[5] + sd[6] + sd[7];
        out[ZQ_ELEMS] = (float)(1.25 * tot / (double)ZQ_ELEMS);
    }
}

extern "C" void kernel_launch(void* const* d_in, const int* in_sizes, int n_in,
                              void* d_out, int out_size, void* d_ws, size_t ws_size,
                              hipStream_t stream) {
    const float* z = (const float*)d_in[0];        // [32,256,64,64] f32
    const float* cb = (const float*)d_in[1];       // [1024,256] f32
    unsigned char* ws = (unsigned char*)d_ws;
    unsigned char* img = ws + WS_IMG;
    float* cbT = (float*)(ws + WS_IMG);            // aliases img (dead after vq_dist)
    float* s2 = (float*)(ws + WS_S2);
    int* idx = (int*)(ws + WS_IDX);
    float* partial = (float*)(ws + WS_PART);
    int* cnt = (int*)(ws + WS_CNT);
    int* list = (int*)(ws + WS_LIST);
    float* out = (float*)d_out;

    vq_prep<<<128, 256, 0, stream>>>(cb, img, cnt);
    vq_s2prep<<<4, 256, 0, stream>>>(cb, s2);
    vq_dist<<<512, 256, 0, stream>>>(z, img, s2, idx, cnt, list);
    vq_cbt<<<4, 256, 0, stream>>>(cb, cbT);
    vq_rescue<<<512, 256, 0, stream>>>(z, cbT, s2, list, cnt, idx);
    vq_gather<<<16384, 256, 0, stream>>>(z, cb, idx, out, partial);
    vq_finalize<<<1, 512, 0, stream>>>(partial, out);
}